// Round 8
// baseline (128.807 us; speedup 1.0000x reference)
//
#include <hip/hip_runtime.h>
#include <hip/hip_bf16.h>
#include <math.h>

// Self_Attention_Local R8: split-wave attention (2 waves per (patch,head) map)
//   k_conv: W permutes (R6-verified) + emb fp32->bf16 (blocks 128..159).
//   k_attn: block = (patch-pair, head), 256 thr, grid 2048, LDS 12 KB.
//     wave (pl = w>>1, hf = w&1): QKV M=16 MFMA staging (R7-verified layouts),
//     stats split 8+8 tiles combined via LDS, folded softmax exp2 (no row max:
//     scores are instance-normalized), S^T->repack->PV 32x32x16 (R7-verified
//     cross-lane repack), ctx swizzle-staged, coalesced bf16 store.
//   k_out: K-split x4 -> fp32 partials (1024 blocks, short chains).
//   k_red: out = sum of 4 partials.

typedef short bfrag  __attribute__((ext_vector_type(8)));   // 8 bf16 = 4 VGPRs
typedef float f32x4  __attribute__((ext_vector_type(4)));
typedef float f32x16 __attribute__((ext_vector_type(16)));

static __device__ __forceinline__ short f2bf(float x) {
    unsigned u = __builtin_bit_cast(unsigned, x);
    return (short)((u + 0x8000u) >> 16);       // round-half-up
}
static __device__ __forceinline__ float fast_exp2(float x) {
#if __has_builtin(__builtin_amdgcn_exp2f)
    return __builtin_amdgcn_exp2f(x);
#else
    return exp2f(x);
#endif
}
static __device__ __forceinline__ bfrag bzero() {
    bfrag z;
    #pragma unroll
    for (int j = 0; j < 8; ++j) z[j] = 0;
    return z;
}

// ---------------- k_conv: weights (R6-verified) + emb -> bf16 ----------------
__global__ __launch_bounds__(256) void k_conv(
    const float* __restrict__ Wq, const float* __restrict__ Wk,
    const float* __restrict__ Wv, const float* __restrict__ Wout,
    const float* __restrict__ emb,
    short* __restrict__ Wp, short* __restrict__ Wout_t, short* __restrict__ emb_bf)
{
    __shared__ short lt[4224];
    const int bid = blockIdx.x, t = threadIdx.x;
    if (bid < 96) {
        const int x = bid >> 5, h = (bid >> 2) & 7, k0 = (bid & 3) * 32;
        const float* W = (x == 0) ? Wq : (x == 1) ? Wk : Wv;
        #pragma unroll 4
        for (int rr = 0; rr < 16; ++rr) {
            const int k = rr * 2 + (t >> 7);
            const int i = t & 127;
            lt[k * 129 + i] = f2bf(W[(k0 + k) * 1024 + i * 8 + h]);
        }
        __syncthreads();
        short* dst = Wp + (x * 8 + h) * 16384;
        #pragma unroll
        for (int pp = 0; pp < 4; ++pp) {
            const int i  = pp * 32 + (t >> 3);
            const int kk = (t & 7) * 4;
            short4 v;
            v.x = lt[(kk + 0) * 129 + i]; v.y = lt[(kk + 1) * 129 + i];
            v.z = lt[(kk + 2) * 129 + i]; v.w = lt[(kk + 3) * 129 + i];
            *(short4*)&dst[i * 128 + k0 + kk] = v;
        }
    } else if (bid < 128) {
        const int b2 = bid - 96;
        const int cq = b2 >> 3, rq = b2 & 7;
        #pragma unroll 4
        for (int ii = 0; ii < 16; ++ii) {
            const int rr = ii * 8 + (t >> 5);
            const int cc = t & 31;
            lt[rr * 33 + cc] = f2bf(Wout[(rq * 128 + rr) * 128 + cq * 32 + cc]);
        }
        __syncthreads();
        #pragma unroll
        for (int ii = 0; ii < 4; ++ii) {
            const int task = ii * 256 + t;
            const int cl = task >> 5, hh = (task >> 2) & 7, mg = task & 3;
            short4 v;
            v.x = lt[(hh + 8 * (mg * 4 + 0)) * 33 + cl];
            v.y = lt[(hh + 8 * (mg * 4 + 1)) * 33 + cl];
            v.z = lt[(hh + 8 * (mg * 4 + 2)) * 33 + cl];
            v.w = lt[(hh + 8 * (mg * 4 + 3)) * 33 + cl];
            *(short4*)&Wout_t[(cq * 32 + cl) * 1024 + hh * 128 + rq * 16 + mg * 4] = v;
        }
    } else {
        const int base = (bid - 128) * 16384;
        #pragma unroll 4
        for (int u = 0; u < 16; ++u) {
            const int off = base + u * 1024 + t * 4;
            const float4 x = *(const float4*)&emb[off];
            short4 v;
            v.x = f2bf(x.x); v.y = f2bf(x.y); v.z = f2bf(x.z); v.w = f2bf(x.w);
            *(short4*)&emb_bf[off] = v;
        }
    }
}

// ---------------- k_attn ----------------
// LDS (shorts): QT 0..2047 Qt[pl][i][p] | KT 2048..4095 Kt[pl][j][p]
//               VS 4096..6143 Vs[pl][p][j] swizzled (ctx overlay after PV)
#define QT 0
#define KT 2048
#define VS 4096

__global__ __launch_bounds__(256) void k_attn(
    const short* __restrict__ emb_bf,   // [4096][128] bf16
    const short* __restrict__ Wp,       // [3][8][128 i][128 k]
    short* __restrict__ ctx2)           // [4096 out-rows][h*128+i] bf16
{
    __shared__ short lds[6144];         // 12 KB
    __shared__ float redS[4], redQ[4];
    const int bid = blockIdx.x;         // 0..2047
    const int pp2 = bid >> 3, h = bid & 7;   // patch-pair, head
    const int t = threadIdx.x;
    const int w = t >> 6, lane = t & 63;
    const int m16 = lane & 15, quad = lane >> 4, q8 = quad * 8;
    const int l31 = lane & 31, hi = lane >> 5;
    const int pl = w >> 1, hf = w & 1;  // wave's patch (local) and band half

    // ===== QKV: (16x128) @ W_h (128x128) x3, 16x16x32 =====
    {
        bfrag a[4];
        #pragma unroll
        for (int ks = 0; ks < 4; ++ks)
            a[ks] = *(const bfrag*)&emb_bf[(size_t)(pp2*16 + m16)*128 + ks*32 + q8];
        #pragma unroll
        for (int tt = 0; tt < 6; ++tt) {
            const int nt = w * 6 + tt;            // 0..23 = {q,k,v} x 8 i-tiles
            const int x  = nt >> 3;
            const int i0 = (nt & 7) * 16;
            const short* Wb = Wp + ((x*8 + h)*128 + i0 + m16) * 128;
            bfrag bb[4];
            #pragma unroll
            for (int ks = 0; ks < 4; ++ks)
                bb[ks] = *(const bfrag*)&Wb[ks*32 + q8];
            f32x4 c0 = {0.f,0.f,0.f,0.f};
            #pragma unroll
            for (int ks = 0; ks < 4; ++ks)
                c0 = __builtin_amdgcn_mfma_f32_16x16x32_bf16(a[ks], bb[ks], c0, 0,0,0);
            // C rows: m = quad*4 + r -> patch plt = quad>>1, token p = (quad&1)*4 + r
            const int plt = quad >> 1;
            const int p0  = (quad & 1) * 4;
            const int col = i0 + m16;
            if (x < 2) {                          // Qt/Kt transposed [i][p]
                short4 v;
                v.x = f2bf(c0[0]); v.y = f2bf(c0[1]);
                v.z = f2bf(c0[2]); v.w = f2bf(c0[3]);
                *(short4*)&lds[(x ? KT : QT) + plt*1024 + col*8 + p0] = v;
            } else {                              // V natural, chunk-swizzled
                #pragma unroll
                for (int r = 0; r < 4; ++r) {
                    const int p = p0 + r;
                    const int phys = ((col >> 3) + p + 2*plt) & 15;
                    lds[VS + plt*1024 + p*128 + phys*8 + (col & 7)] = f2bf(c0[r]);
                }
            }
        }
    }
    __syncthreads();

    // ===== hoist frags (before any overlay writes) =====
    bfrag bv[8];                        // B[k=16kt+8hi+jj][n=p=l31]
    #pragma unroll
    for (int kt = 0; kt < 8; ++kt) {
        if (l31 < 8) {
            const int phys = (2*kt + hi + l31 + 2*pl) & 15;
            bv[kt] = *(const bfrag*)&lds[VS + pl*1024 + l31*128 + phys*8];
        } else if (l31 == 8) {          // ones row -> O[i][8] = rowsum_i
            bfrag o;
            #pragma unroll
            for (int j = 0; j < 8; ++j) o[j] = (short)0x3F80;
            bv[kt] = o;
        } else
            bv[kt] = bzero();
    }
    bfrag ak[4], bq[2];                 // A[m=j][k=p], B[k=p][n=i]
    #pragma unroll
    for (int mt = 0; mt < 4; ++mt)
        ak[mt] = (hi == 0) ? *(const bfrag*)&lds[KT + pl*1024 + (32*mt + l31)*8] : bzero();
    #pragma unroll
    for (int u = 0; u < 2; ++u)
        bq[u] = (hi == 0) ? *(const bfrag*)&lds[QT + pl*1024 + (32*(2*hf+u) + l31)*8] : bzero();

    // ===== stats: this wave's 8 tiles, combine with partner via LDS =====
    float rs2, nbias;
    {
        float ls = 0.f, lq = 0.f;
        #pragma unroll
        for (int u = 0; u < 2; ++u)
            #pragma unroll
            for (int mt = 0; mt < 4; ++mt) {
                f32x16 c = {};
                c = __builtin_amdgcn_mfma_f32_32x32x16_bf16(ak[mt], bq[u], c, 0,0,0);
                #pragma unroll
                for (int r = 0; r < 16; ++r) { ls += c[r]; lq = fmaf(c[r], c[r], lq); }
            }
        #pragma unroll
        for (int off = 1; off <= 32; off <<= 1) {
            ls += __shfl_xor(ls, off);
            lq += __shfl_xor(lq, off);
        }
        if (lane == 0) { redS[w] = ls; redQ[w] = lq; }
        __syncthreads();
        const float st = redS[w] + redS[w ^ 1];
        const float qt = redQ[w] + redQ[w ^ 1];
        const float mean = st * (1.f / 16384.f);
        const float var  = qt * (1.f / 16384.f) - mean * mean;
        rs2   = rsqrtf(var + 1e-5f) * 1.44269504f;       // fold log2(e)
        nbias = -mean * rs2;
    }

    // ===== pass 2: 2 bands (nt = 2hf+u): S^T -> exp -> repack -> PV =====
    #pragma unroll
    for (int u = 0; u < 2; ++u) {
        const int nt = 2*hf + u;
        f32x16 O = {};
        #pragma unroll
        for (int mt = 0; mt < 4; ++mt) {
            f32x16 c = {};
            c = __builtin_amdgcn_mfma_f32_32x32x16_bf16(ak[mt], bq[u], c, 0,0,0);
            short s[16];
            #pragma unroll
            for (int r = 0; r < 16; ++r)
                s[r] = f2bf(fast_exp2(fmaf(c[r], rs2, nbias)));
            // repack C-layout -> PV A-frags (R7-verified mapping)
            #pragma unroll
            for (int g = 0; g < 2; ++g) {
                bfrag ap;
                #pragma unroll
                for (int jj = 0; jj < 4; ++jj) {
                    const int uu = (int)((unsigned short)s[8*g + jj]
                                 | ((unsigned)(unsigned short)s[8*g + 4 + jj] << 16));
                    const int xu = __shfl_xor(uu, 32);
                    const short rem_lo = (short)(xu & 0xffff);
                    const short rem_hi = (short)((unsigned)xu >> 16);
                    ap[jj]     = hi ? rem_hi          : s[8*g + jj];
                    ap[4 + jj] = hi ? s[8*g + 4 + jj] : rem_lo;
                }
                O = __builtin_amdgcn_mfma_f32_32x32x16_bf16(ap, bv[2*mt + g], O, 0,0,0);
            }
        }
        // normalize by rowsum (col p=8) and stage ctx (swizzled)
        #pragma unroll
        for (int g = 0; g < 4; ++g) {
            float v[4];
            #pragma unroll
            for (int qd = 0; qd < 4; ++qd) {
                const int r = 4*g + qd;
                const float srow = __shfl(O[r], hi*32 + 8);
                v[qd] = O[r] * __builtin_amdgcn_rcpf(srow);
            }
            if (l31 < 8) {
                const int physc = (4*nt + g + l31) & 15;
                short4 sv;
                sv.x = f2bf(v[0]); sv.y = f2bf(v[1]);
                sv.z = f2bf(v[2]); sv.w = f2bf(v[3]);
                *(short4*)&lds[VS + pl*1024 + l31*128 + physc*8 + 4*hi] = sv;
            }
        }
    }
    __syncthreads();   // both waves' ctx halves staged

    // ===== ctx -> global ctx2[out_row][h*128+i], coalesced 16B =====
    {
        const int pat = pp2*2 + pl;
        const int bb = pat >> 5, rem = pat & 31;
        const int dd = rem >> 4, hh = (rem >> 2) & 3, ww = rem & 3;
        const int p = hf*4 + quad;
        const int phys = (m16 + p) & 15;
        const bfrag v = *(const bfrag*)&lds[VS + pl*1024 + p*128 + phys*8];
        const int p1 = p >> 2, p2 = (p >> 1) & 1, p3 = p & 1;
        const int row = bb*256 + ((((dd*2 + p1)*4 + hh)*2 + p2)*4 + ww)*2 + p3;
        *(bfrag*)&ctx2[(size_t)row * 1024 + h*128 + m16*8] = v;
    }
}

// ---------------- k_out: K-split x4, partials ----------------
__global__ __launch_bounds__(256) void k_out(
    const short* __restrict__ ctx2,    // [4096][1024]
    const short* __restrict__ Wout_t,  // [128 col][1024 k]
    float* __restrict__ part)          // [4][4096][128]
{
    const int bid = blockIdx.x;        // 0..1023
    const int rt = bid >> 2, kq = bid & 3;
    const int t = threadIdx.x;
    const int w = t >> 6, lane = t & 63;
    const int m16 = lane & 15, quad = lane >> 4, q8 = quad * 8;
    const int row0 = rt * 16;
    const int k0 = kq * 256;

    f32x4 acc0 = {0.f,0.f,0.f,0.f}, acc1 = {0.f,0.f,0.f,0.f};
    const short* ar = ctx2   + (size_t)(row0 + m16) * 1024 + k0 + q8;
    const short* b0 = Wout_t + (size_t)((w*2 + 0)*16 + m16) * 1024 + k0 + q8;
    const short* b1 = Wout_t + (size_t)((w*2 + 1)*16 + m16) * 1024 + k0 + q8;
    #pragma unroll
    for (int ks = 0; ks < 8; ++ks) {
        const bfrag a   = *(const bfrag*)&ar[ks*32];
        const bfrag vb0 = *(const bfrag*)&b0[ks*32];
        const bfrag vb1 = *(const bfrag*)&b1[ks*32];
        acc0 = __builtin_amdgcn_mfma_f32_16x16x32_bf16(a, vb0, acc0, 0, 0, 0);
        acc1 = __builtin_amdgcn_mfma_f32_16x16x32_bf16(a, vb1, acc1, 0, 0, 0);
    }
    float* pb = part + (size_t)kq * 524288;
    const int r0 = quad * 4;
    #pragma unroll
    for (int r = 0; r < 4; ++r) {
        pb[(size_t)(row0 + r0 + r)*128 + (w*2 + 0)*16 + m16] = acc0[r];
        pb[(size_t)(row0 + r0 + r)*128 + (w*2 + 1)*16 + m16] = acc1[r];
    }
}

// ---------------- k_red: out = sum of 4 partials ----------------
__global__ __launch_bounds__(256) void k_red(
    const float* __restrict__ part, float* __restrict__ out)
{
    const int f = blockIdx.x * 256 + threadIdx.x;   // float4 idx, 0..131071
    const f32x4* p4 = (const f32x4*)part;
    f32x4 s = p4[f];
    #pragma unroll
    for (int kq = 1; kq < 4; ++kq)
        s += p4[kq * 131072 + f];
    ((f32x4*)out)[f] = s;
}

extern "C" void kernel_launch(void* const* d_in, const int* in_sizes, int n_in,
                              void* d_out, int out_size, void* d_ws, size_t ws_size,
                              hipStream_t stream) {
    const float* emb  = (const float*)d_in[0];   // (512, 8, 128)
    const float* Wq   = (const float*)d_in[1];   // (128, 1024)
    const float* Wk   = (const float*)d_in[2];
    const float* Wv   = (const float*)d_in[3];
    const float* Wout = (const float*)d_in[4];   // (1024, 128)
    float* out = (float*)d_out;                  // 524288 floats

    short* ctx2   = (short*)d_ws;                // 4194304 shorts (8 MB)
    float* part   = (float*)(ctx2 + 4194304);    // 2097152 floats (8 MB)
    short* Wp     = (short*)(part + 2097152);    // 393216
    short* Wout_t = Wp + 393216;                 // 131072
    short* emb_bf = Wout_t + 131072;             // 524288   (total ~18.05 MB)

    k_conv<<<160, 256, 0, stream>>>(Wq, Wk, Wv, Wout, emb, Wp, Wout_t, emb_bf);
    k_attn<<<2048, 256, 0, stream>>>(emb_bf, Wp, ctx2);
    k_out<<<1024, 256, 0, stream>>>(ctx2, Wout_t, part);
    k_red<<<512, 256, 0, stream>>>(part, out);
}